// Round 8
// baseline (106.344 us; speedup 1.0000x reference)
//
#include <hip/hip_runtime.h>

// N=1536 T=20 H=64 E=16 M=128
// Qf[j,k] (MFMA-frag-tile layout), P[j,k]: fp16 in d_ws; W2f: pre-fragmented
// W2 (16KB fp16). out[i] = max_j relu( relu(Q[j]-P[i]) @ W2 + b2 )
//
// R11: hit the <=128-unified-register frontier. R10's clean A/B (same
// binary, 1.5x wave supply) showed residency is hard-capped at 2 waves/SIMD
// with 160 unified regs -- the HW allocation granule (occupancy steps at
// 64/128/256, m69) rounds 160 up past the 3-wave point. NI=1 (R8) measured
// 80 unified; NI=3 (R9) measured 160; NI=2 should land ~112-128 => 4
// waves/SIMD under the granule. Grid supplies 18 waves/CU (>= the 16 cap).
// Also: explicit zero-reg as MFMA C operand for the ks=0 seed (avoids
// per-tile accvgpr zero-fill). launch_bounds stays (64,2): never squeeze
// the allocator (R5); let residency come from the honest footprint.

#define NN 1536
#define HH 64
#define EE 16
#define MM 128
#define TT 20

#define NI 2
#define NIGRP (NN / NI)       // 768 i-groups
#define JSPLIT 6
#define NTILE (96 / JSPLIT)   // 16 j-tiles of 16 per wave

typedef _Float16 half8 __attribute__((ext_vector_type(8)));
typedef float f32x4 __attribute__((ext_vector_type(4)));

// grid NN, block 128. Computes Qf (frag-tile layout), P, W2f, zero-inits out.
// Qf entry: A[row=j&15][k=m] for tile jt=j>>4 lands where reading lane
// l finds halfs jj at ((jt*4+ks)*64+l)*8+jj with k = ks*32 + (l>>4)*8 + jj
//   ->  ks=m>>5, l=((m>>3)&3)*16+(j&15), jj=m&7.   (verified R6-R10)
__global__ __launch_bounds__(128) void precompute_kernel(
    const float* __restrict__ hidden, const float* __restrict__ gt,
    const float* __restrict__ We, const float* __restrict__ be,
    const float* __restrict__ W1, const float* __restrict__ b1,
    const float* __restrict__ W2,
    _Float16* __restrict__ Qf, _Float16* __restrict__ P,
    _Float16* __restrict__ W2f, float* __restrict__ out)
{
  const int j = blockIdx.x;
  const int m = threadIdx.x;
  const float* hrow = hidden + j * HH;
  float a0 = 0.f, a1 = 0.f;
  #pragma unroll 8
  for (int h = 0; h < HH; h += 2) {
    a0 = fmaf(hrow[h],     W1[h * MM + m],       a0);
    a1 = fmaf(hrow[h + 1], W1[(h + 1) * MM + m], a1);
  }
  const float a = a0 + a1;
  float ve0 = 0.f, ve1 = 0.f, cm = b1[m];
  #pragma unroll
  for (int e = 0; e < EE; ++e) {
    float w1e = W1[(HH + e) * MM + m];
    ve0 = fmaf(We[e], w1e, ve0);       // We[0][e]
    ve1 = fmaf(We[EE + e], w1e, ve1);  // We[1][e]
    cm  = fmaf(be[e], w1e, cm);
  }
  const float e0 = gt[j * (2 * TT) + 2 * (TT - 1)];
  const float e1 = gt[j * (2 * TT) + 2 * (TT - 1) + 1];
  const float p = fmaf(e0, ve0, e1 * ve1);
  P[j * MM + m] = (_Float16)p;

  const int jt = j >> 4;
  const int ks = m >> 5;
  const int ln = ((m >> 3) & 3) * 16 + (j & 15);
  const int jj = m & 7;
  Qf[(((jt * 4) + ks) * 64 + ln) * 8 + jj] = (_Float16)(a + p + cm);

  if (m < HH) out[j * HH + m] = 0.f;

  // blocks 0..7: pre-fragment W2 -> W2f (verified R8-R10).
  // unit u = ct*256 + ksx*64 + l holds halfs jj with
  // W2f[u*8+jj] = (fp16) W2[(ksx*32 + (l>>4)*8 + jj)*HH + ct*16 + (l&15)]
  if (j < 8) {
    const int u = j * 128 + m;          // 0..1023
    const int ct = u >> 8;
    const int ksx = (u >> 6) & 3;
    const int l = u & 63;
    half8 w;
    #pragma unroll
    for (int t = 0; t < 8; ++t)
      w[t] = (_Float16)W2[(ksx * 32 + (l >> 4) * 8 + t) * HH + ct * 16 + (l & 15)];
    *(half8*)(W2f + (size_t)u * 8) = w;
  }
}

// grid NIGRP*JSPLIT = 4608, block 64 (1 wave). Wave: i0,i0+1, 16 j-tiles.
// Fully independent waves; Q tiles direct from L1/L2; 32 MFMA per 4 loads.
__global__ __launch_bounds__(64, 2) void pairmlp_max_kernel(
    const _Float16* __restrict__ Qf, const _Float16* __restrict__ P,
    const _Float16* __restrict__ W2f, const float* __restrict__ b2,
    float* __restrict__ out)
{
  const int lane = threadIdx.x;
  const int quad = lane >> 4;
  const int lcol = lane & 15;
  const int ig = blockIdx.x % NIGRP;  // consecutive blocks: same js ->
  const int js = blockIdx.x / NIGRP;  // same Q tile stream (L1/L2 reuse)
  const int i0 = ig * NI;

  // B fragments from pre-fragmented W2f: 16 coalesced 16B loads
  half8 bfrag[4][4];
  {
    const half8* wf = (const half8*)W2f + lane;
    #pragma unroll
    for (int ct = 0; ct < 4; ++ct)
      #pragma unroll
      for (int ks = 0; ks < 4; ++ks)
        bfrag[ct][ks] = wf[(ct * 4 + ks) * 64];
  }

  // P fragments for NI i's
  half8 pv[NI][4];
  #pragma unroll
  for (int ii = 0; ii < NI; ++ii) {
    const _Float16* prow = P + (i0 + ii) * MM + quad * 8;
    #pragma unroll
    for (int ks = 0; ks < 4; ++ks)
      pv[ii][ks] = *(const half8*)(prow + ks * 32);
  }

  float b2v[4];
  #pragma unroll
  for (int ct = 0; ct < 4; ++ct) b2v[ct] = b2[ct * 16 + lcol];

  float rmax[NI][4];
  #pragma unroll
  for (int ii = 0; ii < NI; ++ii)
    #pragma unroll
    for (int ct = 0; ct < 4; ++ct) rmax[ii][ct] = -3.0e38f;

  const int jt0 = js * NTILE;
  // tile = 256 half8 units (16 j x 128 k); lane-linear within (tile, ks)
  const half8* qbase = (const half8*)Qf + (size_t)jt0 * 256 + lane;

  const half8 hz = 0;
  const f32x4 fz = {0.f, 0.f, 0.f, 0.f};  // zero C operand (no accvgpr fill)

  // compute one 16-j tile held in qt[4] against all NI i's
  auto compute_tile = [&](const half8* qt) {
    f32x4 acc[NI][4];
    #pragma unroll
    for (int ks = 0; ks < 4; ++ks) {
      __builtin_amdgcn_s_setprio(1);
      #pragma unroll
      for (int ii = 0; ii < NI; ++ii) {
        half8 s = qt[ks] - pv[ii][ks];
        s = __builtin_elementwise_max(s, hz);
        #pragma unroll
        for (int ct = 0; ct < 4; ++ct) {
          if (ks == 0)
            acc[ii][ct] = __builtin_amdgcn_mfma_f32_16x16x32_f16(
                s, bfrag[ct][0], fz, 0, 0, 0);
          else
            acc[ii][ct] = __builtin_amdgcn_mfma_f32_16x16x32_f16(
                s, bfrag[ct][ks], acc[ii][ct], 0, 0, 0);
        }
      }
      __builtin_amdgcn_s_setprio(0);
    }
    // C/D: col=lcol+ct*16, row(j)=quad*4+reg. Raw max; +b2/relu deferred.
    #pragma unroll
    for (int ii = 0; ii < NI; ++ii)
      #pragma unroll
      for (int ct = 0; ct < 4; ++ct) {
        const float t3 = fmaxf(fmaxf(acc[ii][ct][0], acc[ii][ct][1]), acc[ii][ct][2]);
        rmax[ii][ct] = fmaxf(fmaxf(t3, acc[ii][ct][3]), rmax[ii][ct]);
      }
  };

  // prefetch tile 0 into qc
  half8 qc[4], qn[4];
  #pragma unroll
  for (int ks = 0; ks < 4; ++ks) qc[ks] = qbase[ks * 64];

  // 2x-unrolled ping-pong: no qc<-qn register copies
  for (int t = 0; t < NTILE; t += 2) {
    // prefetch tile t+1 into qn
    #pragma unroll
    for (int ks = 0; ks < 4; ++ks)
      qn[ks] = qbase[(size_t)(t + 1) * 256 + ks * 64];
    compute_tile(qc);  // tile t

    // prefetch tile t+2 into qc (dummy tile 0 on last pair; unused)
    const int t2 = (t + 2 < NTILE) ? (t + 2) : 0;
    #pragma unroll
    for (int ks = 0; ks < 4; ++ks)
      qc[ks] = qbase[(size_t)t2 * 256 + ks * 64];
    compute_tile(qn);  // tile t+1
  }

  // combine quad-groups (different j rows, same col), then atomic max.
  #pragma unroll
  for (int ii = 0; ii < NI; ++ii)
    #pragma unroll
    for (int ct = 0; ct < 4; ++ct) {
      float v = rmax[ii][ct];
      v = fmaxf(v, __shfl_xor(v, 16, 64));
      v = fmaxf(v, __shfl_xor(v, 32, 64));
      v = fmaxf(v + b2v[ct], 0.f);
      if (quad == 0)
        atomicMax((unsigned*)(out + (i0 + ii) * HH + ct * 16 + lcol), __float_as_uint(v));
    }
}

extern "C" void kernel_launch(void* const* d_in, const int* in_sizes, int n_in,
                              void* d_out, int out_size, void* d_ws, size_t ws_size,
                              hipStream_t stream) {
  const float* hidden = (const float*)d_in[0];
  const float* gt     = (const float*)d_in[1];
  const float* We     = (const float*)d_in[2];
  const float* be     = (const float*)d_in[3];
  const float* W1     = (const float*)d_in[4];
  const float* b1     = (const float*)d_in[5];
  const float* W2     = (const float*)d_in[6];
  const float* b2     = (const float*)d_in[7];
  float* out = (float*)d_out;

  _Float16* Qf  = (_Float16*)d_ws;     // NN*MM fp16 (384KB), frag-tile layout
  _Float16* Ph  = Qf + NN * MM;        // NN*MM fp16 (384KB)
  _Float16* W2f = Ph + NN * MM;        // 4*4*64*8 fp16 (16KB), frag layout

  precompute_kernel<<<NN, 128, 0, stream>>>(hidden, gt, We, be, W1, b1, W2, Qf, Ph, W2f, out);
  pairmlp_max_kernel<<<NIGRP * JSPLIT, 64, 0, stream>>>(Qf, Ph, W2f, b2, out);
}

// Round 9
// 103.877 us; speedup vs baseline: 1.0237x; 1.0237x over previous
//
#include <hip/hip_runtime.h>

// N=1536 T=20 H=64 E=16 M=128
// Qf[j,k] (MFMA-frag-tile layout), P[j,k]: fp16 in d_ws; W2f: pre-fragmented
// W2 (16KB fp16). out[i] = max_j relu( relu(Q[j]-P[i]) @ W2 + b2 )
//
// R12: R9's winning per-wave structure (NI=3, 48 MFMA per 4 tile loads --
// the only lever that has moved duration), repackaged 4 independent waves
// per 256-thread block. Evidence R4-R11: 64-thr blocks always read ~5
// waves/CU resident (occ 15-18%) regardless of supply (8-18/CU) or
// footprint (64-160 unified regs); 256-thr blocks (R6/R7) read ~7.8/CU.
// The cap is workgroup-dispatch shape, not registers. No barriers, no LDS,
// no shared state -- wid selects the (ig,js) slice; waves in a block get
// consecutive ig at the SAME js => they stream identical Q tiles => L1
// sharing. Grid 512x4waves = same 2048 assignments as R9; per-wave codegen
// identical (VGPR_Count ~112 is the control).

#define NN 1536
#define HH 64
#define EE 16
#define MM 128
#define TT 20

#define NI 3
#define NIGRP (NN / NI)       // 512 i-groups
#define JSPLIT 4
#define NTILE (96 / JSPLIT)   // 24 j-tiles of 16 per wave
#define BWAVES 4              // independent waves per block

typedef _Float16 half8 __attribute__((ext_vector_type(8)));
typedef float f32x4 __attribute__((ext_vector_type(4)));

// grid NN, block 128. Computes Qf (frag-tile layout), P, W2f, zero-inits out.
// Qf entry: A[row=j&15][k=m] for tile jt=j>>4 lands where reading lane
// l finds halfs jj at ((jt*4+ks)*64+l)*8+jj with k = ks*32 + (l>>4)*8 + jj
//   ->  ks=m>>5, l=((m>>3)&3)*16+(j&15), jj=m&7.   (verified R6-R11)
__global__ __launch_bounds__(128) void precompute_kernel(
    const float* __restrict__ hidden, const float* __restrict__ gt,
    const float* __restrict__ We, const float* __restrict__ be,
    const float* __restrict__ W1, const float* __restrict__ b1,
    const float* __restrict__ W2,
    _Float16* __restrict__ Qf, _Float16* __restrict__ P,
    _Float16* __restrict__ W2f, float* __restrict__ out)
{
  const int j = blockIdx.x;
  const int m = threadIdx.x;
  const float* hrow = hidden + j * HH;
  float a0 = 0.f, a1 = 0.f;
  #pragma unroll 8
  for (int h = 0; h < HH; h += 2) {
    a0 = fmaf(hrow[h],     W1[h * MM + m],       a0);
    a1 = fmaf(hrow[h + 1], W1[(h + 1) * MM + m], a1);
  }
  const float a = a0 + a1;
  float ve0 = 0.f, ve1 = 0.f, cm = b1[m];
  #pragma unroll
  for (int e = 0; e < EE; ++e) {
    float w1e = W1[(HH + e) * MM + m];
    ve0 = fmaf(We[e], w1e, ve0);       // We[0][e]
    ve1 = fmaf(We[EE + e], w1e, ve1);  // We[1][e]
    cm  = fmaf(be[e], w1e, cm);
  }
  const float e0 = gt[j * (2 * TT) + 2 * (TT - 1)];
  const float e1 = gt[j * (2 * TT) + 2 * (TT - 1) + 1];
  const float p = fmaf(e0, ve0, e1 * ve1);
  P[j * MM + m] = (_Float16)p;

  const int jt = j >> 4;
  const int ks = m >> 5;
  const int ln = ((m >> 3) & 3) * 16 + (j & 15);
  const int jj = m & 7;
  Qf[(((jt * 4) + ks) * 64 + ln) * 8 + jj] = (_Float16)(a + p + cm);

  if (m < HH) out[j * HH + m] = 0.f;

  // blocks 0..7: pre-fragment W2 -> W2f (verified R8-R11).
  // unit u = ct*256 + ksx*64 + l holds halfs jj with
  // W2f[u*8+jj] = (fp16) W2[(ksx*32 + (l>>4)*8 + jj)*HH + ct*16 + (l&15)]
  if (j < 8) {
    const int u = j * 128 + m;          // 0..1023
    const int ct = u >> 8;
    const int ksx = (u >> 6) & 3;
    const int l = u & 63;
    half8 w;
    #pragma unroll
    for (int t = 0; t < 8; ++t)
      w[t] = (_Float16)W2[(ksx * 32 + (l >> 4) * 8 + t) * HH + ct * 16 + (l & 15)];
    *(half8*)(W2f + (size_t)u * 8) = w;
  }
}

// grid NIGRP*JSPLIT/BWAVES = 512 blocks, 256 threads (4 INDEPENDENT waves).
// Wave gid = bid*4+wid: i0 = (gid%NIGRP)*NI, js = gid/NIGRP. 48 MFMA/4 loads.
__global__ __launch_bounds__(256, 2) void pairmlp_max_kernel(
    const _Float16* __restrict__ Qf, const _Float16* __restrict__ P,
    const _Float16* __restrict__ W2f, const float* __restrict__ b2,
    float* __restrict__ out)
{
  const int lane = threadIdx.x & 63;
  const int wid  = threadIdx.x >> 6;
  const int quad = lane >> 4;
  const int lcol = lane & 15;
  const int gid = blockIdx.x * BWAVES + wid;
  const int ig = gid % NIGRP;  // waves in a block: consecutive ig,
  const int js = gid / NIGRP;  // same js -> identical Q tile stream (L1 share)
  const int i0 = ig * NI;

  // B fragments from pre-fragmented W2f: 16 coalesced 16B loads
  half8 bfrag[4][4];
  {
    const half8* wf = (const half8*)W2f + lane;
    #pragma unroll
    for (int ct = 0; ct < 4; ++ct)
      #pragma unroll
      for (int ks = 0; ks < 4; ++ks)
        bfrag[ct][ks] = wf[(ct * 4 + ks) * 64];
  }

  // P fragments for NI i's
  half8 pv[NI][4];
  #pragma unroll
  for (int ii = 0; ii < NI; ++ii) {
    const _Float16* prow = P + (i0 + ii) * MM + quad * 8;
    #pragma unroll
    for (int ks = 0; ks < 4; ++ks)
      pv[ii][ks] = *(const half8*)(prow + ks * 32);
  }

  float b2v[4];
  #pragma unroll
  for (int ct = 0; ct < 4; ++ct) b2v[ct] = b2[ct * 16 + lcol];

  float rmax[NI][4];
  #pragma unroll
  for (int ii = 0; ii < NI; ++ii)
    #pragma unroll
    for (int ct = 0; ct < 4; ++ct) rmax[ii][ct] = -3.0e38f;

  const int jt0 = js * NTILE;
  // tile = 256 half8 units (16 j x 128 k); lane-linear within (tile, ks)
  const half8* qbase = (const half8*)Qf + (size_t)jt0 * 256 + lane;

  const half8 hz = 0;

  // compute one 16-j tile held in qt[4] against all NI i's
  auto compute_tile = [&](const half8* qt) {
    f32x4 acc[NI][4];
    #pragma unroll
    for (int ks = 0; ks < 4; ++ks) {
      __builtin_amdgcn_s_setprio(1);
      #pragma unroll
      for (int ii = 0; ii < NI; ++ii) {
        half8 s = qt[ks] - pv[ii][ks];
        s = __builtin_elementwise_max(s, hz);
        #pragma unroll
        for (int ct = 0; ct < 4; ++ct) {
          if (ks == 0)
            acc[ii][ct] = __builtin_amdgcn_mfma_f32_16x16x32_f16(
                s, bfrag[ct][0], f32x4{0.f, 0.f, 0.f, 0.f}, 0, 0, 0);
          else
            acc[ii][ct] = __builtin_amdgcn_mfma_f32_16x16x32_f16(
                s, bfrag[ct][ks], acc[ii][ct], 0, 0, 0);
        }
      }
      __builtin_amdgcn_s_setprio(0);
    }
    // C/D: col=lcol+ct*16, row(j)=quad*4+reg. Raw max; +b2/relu deferred.
    #pragma unroll
    for (int ii = 0; ii < NI; ++ii)
      #pragma unroll
      for (int ct = 0; ct < 4; ++ct) {
        const float t3 = fmaxf(fmaxf(acc[ii][ct][0], acc[ii][ct][1]), acc[ii][ct][2]);
        rmax[ii][ct] = fmaxf(fmaxf(t3, acc[ii][ct][3]), rmax[ii][ct]);
      }
  };

  // prefetch tile 0 into qc
  half8 qc[4], qn[4];
  #pragma unroll
  for (int ks = 0; ks < 4; ++ks) qc[ks] = qbase[ks * 64];

  // 2x-unrolled ping-pong: no qc<-qn register copies
  for (int t = 0; t < NTILE; t += 2) {
    // prefetch tile t+1 into qn
    #pragma unroll
    for (int ks = 0; ks < 4; ++ks)
      qn[ks] = qbase[(size_t)(t + 1) * 256 + ks * 64];
    compute_tile(qc);  // tile t

    // prefetch tile t+2 into qc (dummy tile 0 on last pair; unused)
    const int t2 = (t + 2 < NTILE) ? (t + 2) : 0;
    #pragma unroll
    for (int ks = 0; ks < 4; ++ks)
      qc[ks] = qbase[(size_t)t2 * 256 + ks * 64];
    compute_tile(qn);  // tile t+1
  }

  // combine quad-groups (different j rows, same col), then atomic max.
  #pragma unroll
  for (int ii = 0; ii < NI; ++ii)
    #pragma unroll
    for (int ct = 0; ct < 4; ++ct) {
      float v = rmax[ii][ct];
      v = fmaxf(v, __shfl_xor(v, 16, 64));
      v = fmaxf(v, __shfl_xor(v, 32, 64));
      v = fmaxf(v + b2v[ct], 0.f);
      if (quad == 0)
        atomicMax((unsigned*)(out + (i0 + ii) * HH + ct * 16 + lcol), __float_as_uint(v));
    }
}

extern "C" void kernel_launch(void* const* d_in, const int* in_sizes, int n_in,
                              void* d_out, int out_size, void* d_ws, size_t ws_size,
                              hipStream_t stream) {
  const float* hidden = (const float*)d_in[0];
  const float* gt     = (const float*)d_in[1];
  const float* We     = (const float*)d_in[2];
  const float* be     = (const float*)d_in[3];
  const float* W1     = (const float*)d_in[4];
  const float* b1     = (const float*)d_in[5];
  const float* W2     = (const float*)d_in[6];
  const float* b2     = (const float*)d_in[7];
  float* out = (float*)d_out;

  _Float16* Qf  = (_Float16*)d_ws;     // NN*MM fp16 (384KB), frag-tile layout
  _Float16* Ph  = Qf + NN * MM;        // NN*MM fp16 (384KB)
  _Float16* W2f = Ph + NN * MM;        // 4*4*64*8 fp16 (16KB), frag layout

  precompute_kernel<<<NN, 128, 0, stream>>>(hidden, gt, We, be, W1, b1, W2, Qf, Ph, W2f, out);
  pairmlp_max_kernel<<<(NIGRP * JSPLIT) / BWAVES, 256, 0, stream>>>(Qf, Ph, W2f, b2, out);
}

// Round 10
// 102.624 us; speedup vs baseline: 1.0362x; 1.0122x over previous
//
#include <hip/hip_runtime.h>

// N=1536 T=20 H=64 E=16 M=128
// Qf[j,k] (MFMA-frag-tile layout), P[j,k]: fp16 in d_ws; W2f: pre-fragmented
// W2 (16KB fp16). out[i] = max_j relu( relu(Q[j]-P[i]) @ W2 + b2 )
//
// R13: break the phase-lock + trim addressing VALU, on the proven R9
// structure. Ledger (R9/R12): wall 104k cyc/SIMD, matrix 44.7k (43%),
// static VALU ~13%, ~44% STALL. Co-resident waves run identical code
// started together -> in-phase lock: MFMA phases contend on the matrix
// pipe, VALU phases coincide; no cross-wave overlap.
//  (a) stagger: odd blocks process tiles [12..24)+[0..12), even [0..12)+
//      [12..24) -- mixed-parity SIMD pairs anti-phase (MFMA over VALU).
//  (b) byte-pointer tile addressing, loads at imm offsets 0/1024/2048/3072,
//      pointer bump once per 2 tiles: kills 64-bit mul chains (~35 VALU/tile).
// Else identical to R9/R12: NI=3 (48 MFMA per 4 loads -- only lever that
// ever moved duration), W2f pre-frag, frag-layout Q loads, setprio, 64-thr
// blocks, JSPLIT=4, grid 2048.

#define NN 1536
#define HH 64
#define EE 16
#define MM 128
#define TT 20

#define NI 3
#define NIGRP (NN / NI)       // 512 i-groups
#define JSPLIT 4
#define NTILE (96 / JSPLIT)   // 24 j-tiles of 16 per wave
#define HTILE (NTILE / 2)     // 12 per half-run

typedef _Float16 half8 __attribute__((ext_vector_type(8)));
typedef float f32x4 __attribute__((ext_vector_type(4)));

// grid NN, block 128. Computes Qf (frag-tile layout), P, W2f, zero-inits out.
// Qf entry: A[row=j&15][k=m] for tile jt=j>>4 lands where reading lane
// l finds halfs jj at ((jt*4+ks)*64+l)*8+jj with k = ks*32 + (l>>4)*8 + jj
//   ->  ks=m>>5, l=((m>>3)&3)*16+(j&15), jj=m&7.   (verified R6-R12)
__global__ __launch_bounds__(128) void precompute_kernel(
    const float* __restrict__ hidden, const float* __restrict__ gt,
    const float* __restrict__ We, const float* __restrict__ be,
    const float* __restrict__ W1, const float* __restrict__ b1,
    const float* __restrict__ W2,
    _Float16* __restrict__ Qf, _Float16* __restrict__ P,
    _Float16* __restrict__ W2f, float* __restrict__ out)
{
  const int j = blockIdx.x;
  const int m = threadIdx.x;
  const float* hrow = hidden + j * HH;
  float a0 = 0.f, a1 = 0.f;
  #pragma unroll 8
  for (int h = 0; h < HH; h += 2) {
    a0 = fmaf(hrow[h],     W1[h * MM + m],       a0);
    a1 = fmaf(hrow[h + 1], W1[(h + 1) * MM + m], a1);
  }
  const float a = a0 + a1;
  float ve0 = 0.f, ve1 = 0.f, cm = b1[m];
  #pragma unroll
  for (int e = 0; e < EE; ++e) {
    float w1e = W1[(HH + e) * MM + m];
    ve0 = fmaf(We[e], w1e, ve0);       // We[0][e]
    ve1 = fmaf(We[EE + e], w1e, ve1);  // We[1][e]
    cm  = fmaf(be[e], w1e, cm);
  }
  const float e0 = gt[j * (2 * TT) + 2 * (TT - 1)];
  const float e1 = gt[j * (2 * TT) + 2 * (TT - 1) + 1];
  const float p = fmaf(e0, ve0, e1 * ve1);
  P[j * MM + m] = (_Float16)p;

  const int jt = j >> 4;
  const int ks = m >> 5;
  const int ln = ((m >> 3) & 3) * 16 + (j & 15);
  const int jj = m & 7;
  Qf[(((jt * 4) + ks) * 64 + ln) * 8 + jj] = (_Float16)(a + p + cm);

  if (m < HH) out[j * HH + m] = 0.f;

  // blocks 0..7: pre-fragment W2 -> W2f (verified R8-R12).
  // unit u = ct*256 + ksx*64 + l holds halfs jj with
  // W2f[u*8+jj] = (fp16) W2[(ksx*32 + (l>>4)*8 + jj)*HH + ct*16 + (l&15)]
  if (j < 8) {
    const int u = j * 128 + m;          // 0..1023
    const int ct = u >> 8;
    const int ksx = (u >> 6) & 3;
    const int l = u & 63;
    half8 w;
    #pragma unroll
    for (int t = 0; t < 8; ++t)
      w[t] = (_Float16)W2[(ksx * 32 + (l >> 4) * 8 + t) * HH + ct * 16 + (l & 15)];
    *(half8*)(W2f + (size_t)u * 8) = w;
  }
}

// grid NIGRP*JSPLIT = 2048, block 64 (1 wave). Wave: i0..i0+2, 24 j-tiles
// in two half-runs of 12, order swapped by blockIdx parity (anti-phase).
__global__ __launch_bounds__(64, 2) void pairmlp_max_kernel(
    const _Float16* __restrict__ Qf, const _Float16* __restrict__ P,
    const _Float16* __restrict__ W2f, const float* __restrict__ b2,
    float* __restrict__ out)
{
  const int lane = threadIdx.x;
  const int quad = lane >> 4;
  const int lcol = lane & 15;
  const int ig = blockIdx.x % NIGRP;  // consecutive blocks: same js ->
  const int js = blockIdx.x / NIGRP;  // same Q tile stream (L1/L2 reuse)
  const int i0 = ig * NI;
  const int par = blockIdx.x & 1;     // stagger parity

  // B fragments from pre-fragmented W2f: 16 coalesced 16B loads
  half8 bfrag[4][4];
  {
    const half8* wf = (const half8*)W2f + lane;
    #pragma unroll
    for (int ct = 0; ct < 4; ++ct)
      #pragma unroll
      for (int ks = 0; ks < 4; ++ks)
        bfrag[ct][ks] = wf[(ct * 4 + ks) * 64];
  }

  // P fragments for NI i's
  half8 pv[NI][4];
  #pragma unroll
  for (int ii = 0; ii < NI; ++ii) {
    const _Float16* prow = P + (i0 + ii) * MM + quad * 8;
    #pragma unroll
    for (int ks = 0; ks < 4; ++ks)
      pv[ii][ks] = *(const half8*)(prow + ks * 32);
  }

  float b2v[4];
  #pragma unroll
  for (int ct = 0; ct < 4; ++ct) b2v[ct] = b2[ct * 16 + lcol];

  float rmax[NI][4];
  #pragma unroll
  for (int ii = 0; ii < NI; ++ii)
    #pragma unroll
    for (int ct = 0; ct < 4; ++ct) rmax[ii][ct] = -3.0e38f;

  // byte base: tile jt at jt*4096, ks at +1024*ks, lane at +16*lane
  const char* qbytes = (const char*)Qf + (size_t)(js * NTILE) * 4096 + lane * 16;

  const half8 hz = 0;

  // compute one 16-j tile held in qt[4] against all NI i's
  auto compute_tile = [&](const half8* qt) {
    f32x4 acc[NI][4];
    #pragma unroll
    for (int ks = 0; ks < 4; ++ks) {
      __builtin_amdgcn_s_setprio(1);
      #pragma unroll
      for (int ii = 0; ii < NI; ++ii) {
        half8 s = qt[ks] - pv[ii][ks];
        s = __builtin_elementwise_max(s, hz);
        #pragma unroll
        for (int ct = 0; ct < 4; ++ct) {
          if (ks == 0)
            acc[ii][ct] = __builtin_amdgcn_mfma_f32_16x16x32_f16(
                s, bfrag[ct][0], f32x4{0.f, 0.f, 0.f, 0.f}, 0, 0, 0);
          else
            acc[ii][ct] = __builtin_amdgcn_mfma_f32_16x16x32_f16(
                s, bfrag[ct][ks], acc[ii][ct], 0, 0, 0);
        }
      }
      __builtin_amdgcn_s_setprio(0);
    }
    // C/D: col=lcol+ct*16, row(j)=quad*4+reg. Raw max; +b2/relu deferred.
    #pragma unroll
    for (int ii = 0; ii < NI; ++ii)
      #pragma unroll
      for (int ct = 0; ct < 4; ++ct) {
        const float t3 = fmaxf(fmaxf(acc[ii][ct][0], acc[ii][ct][1]), acc[ii][ct][2]);
        rmax[ii][ct] = fmaxf(fmaxf(t3, acc[ii][ct][3]), rmax[ii][ct]);
      }
  };

  half8 qc[4], qn[4];

  // two half-runs of HTILE tiles; order swapped by parity (anti-phase stagger)
  for (int h = 0; h < 2; ++h) {
    const char* runb = qbytes + (((h ^ par) != 0) ? HTILE * 4096 : 0);
    const char* qp = runb;

    // prime qc from first tile of this run
    #pragma unroll
    for (int ks = 0; ks < 4; ++ks)
      qc[ks] = *(const half8*)(qp + ks * 1024);

    for (int t = 0; t < HTILE; t += 2) {
      // prefetch tile t+1 (imm offsets off qp+4096)
      #pragma unroll
      for (int ks = 0; ks < 4; ++ks)
        qn[ks] = *(const half8*)(qp + 4096 + ks * 1024);
      compute_tile(qc);  // tile t

      // prefetch tile t+2 (dummy run-start on last pair; unused)
      const char* q2 = (t + 2 < HTILE) ? (qp + 8192) : runb;
      #pragma unroll
      for (int ks = 0; ks < 4; ++ks)
        qc[ks] = *(const half8*)(q2 + ks * 1024);
      compute_tile(qn);  // tile t+1

      qp += 8192;
    }
  }

  // combine quad-groups (different j rows, same col), then atomic max.
  #pragma unroll
  for (int ii = 0; ii < NI; ++ii)
    #pragma unroll
    for (int ct = 0; ct < 4; ++ct) {
      float v = rmax[ii][ct];
      v = fmaxf(v, __shfl_xor(v, 16, 64));
      v = fmaxf(v, __shfl_xor(v, 32, 64));
      v = fmaxf(v + b2v[ct], 0.f);
      if (quad == 0)
        atomicMax((unsigned*)(out + (i0 + ii) * HH + ct * 16 + lcol), __float_as_uint(v));
    }
}

extern "C" void kernel_launch(void* const* d_in, const int* in_sizes, int n_in,
                              void* d_out, int out_size, void* d_ws, size_t ws_size,
                              hipStream_t stream) {
  const float* hidden = (const float*)d_in[0];
  const float* gt     = (const float*)d_in[1];
  const float* We     = (const float*)d_in[2];
  const float* be     = (const float*)d_in[3];
  const float* W1     = (const float*)d_in[4];
  const float* b1     = (const float*)d_in[5];
  const float* W2     = (const float*)d_in[6];
  const float* b2     = (const float*)d_in[7];
  float* out = (float*)d_out;

  _Float16* Qf  = (_Float16*)d_ws;     // NN*MM fp16 (384KB), frag-tile layout
  _Float16* Ph  = Qf + NN * MM;        // NN*MM fp16 (384KB)
  _Float16* W2f = Ph + NN * MM;        // 4*4*64*8 fp16 (16KB), frag layout

  precompute_kernel<<<NN, 128, 0, stream>>>(hidden, gt, We, be, W1, b1, W2, Qf, Ph, W2f, out);
  pairmlp_max_kernel<<<NIGRP * JSPLIT, 64, 0, stream>>>(Qf, Ph, W2f, b2, out);
}